// Round 12
// baseline (499.320 us; speedup 1.0000x reference)
//
#include <hip/hip_runtime.h>
#include <hip/hip_bf16.h>

// ---------------------------------------------------------------------------
// PUSCH neural detector: 4 stacked ConvLSTM layers on [B=2,T=14,H=1536,W=1].
// 3x3 conv degenerates to width-3 conv along H (kw=1 slice).
// R17 (482us): GEMM = A macro-chunk LDS + fragment-major B global->VGPR;
// scan = trapezoid (OWN=16, WIN=48, 192 blocks). Scan ladder: R18/R19
// neutral, R20 prefetch SPILLED (VGPR-bound), R21 fine-strips HBM-bound,
// R22 XCD-swizzle neutral. R23: LDS-double-buffered xz prefetch via
// global_load_lds — the GEMM's proven issue-after-barrier/drain-at-next-
// barrier pattern, at ZERO VGPR cost. Step t issues t+1's 48-row window as
// 12 fire-and-forget 1KB wave-loads/wave into Xs[nxt]; the end-of-step
// barrier drain hides them behind a full step of MFMA+gates. Gates read xz
// from LDS. Edge chunks never issued; their LDS slots zeroed once (zeros
// persist). Frontier mask dropped: garbage rows bounded either way;
// in-frontier rows read identical xz -> valid outputs bit-exact.
// ---------------------------------------------------------------------------

#define BB   2
#define TT   14
#define LL   1536
#define LL2  1538                 // padded rows: zero row 0, zero row 1537
#define CINR 297
#define CP_IN 320                 // padded input channels (10 chunks of 32)
#define NSTRIP 96                 // LL / 16
#define NBLK  (BB * NSTRIP)       // 192 scan blocks
#define WIN  48                   // scan window rows (own 16 + 16 halo each side)

typedef __attribute__((ext_vector_type(8))) short short8;   // 8 bf16 = 4 VGPRs
typedef __attribute__((ext_vector_type(4))) float floatx4;  // MFMA C/D

// ---- workspace layout (float units) ---------------------------------------
static constexpr size_t U_WBIN_HI  = 0;         // Bp [10cc][3kh][16g][64lane][8]
static constexpr size_t U_WBIN_LO  = 245760;
static constexpr size_t U_WBR0_HI  = 491520;    // Bp [2][3][16][64][8]
static constexpr size_t U_WBR0_LO  = 540672;
static constexpr size_t U_WBR1_HI  = 589824;
static constexpr size_t U_WBR1_LO  = 638976;
static constexpr size_t U_WBOUT_HI = 688128;    // Bp [2][3][8][64][8]
static constexpr size_t U_WBOUT_LO = 712704;
static constexpr size_t U_WHTIN    = 737280;    // [256][192] scan WhT bf16
static constexpr size_t U_WHTR0    = 786432;
static constexpr size_t U_WHTR1    = 835584;
static constexpr size_t U_WHTOUT   = 884736;    // [128][96]
static constexpr size_t OFF_BIN   = 448512;     // f32 gate-interleaved biases
static constexpr size_t OFF_BR0   = 448768;
static constexpr size_t OFF_BR1   = 449024;
static constexpr size_t OFF_BOUT  = 449280;
static constexpr size_t OFF_Z0HI  = 458752;     // u16 plane [28][1538][320]
static constexpr size_t SZ_Z0PL   = 6890240;    // 28*1538*320/2 floats
static constexpr size_t OFF_Z0LO  = OFF_Z0HI + SZ_Z0PL;
static constexpr size_t OFF_XZ    = OFF_Z0LO + SZ_Z0PL;
static constexpr size_t SZ_XZ     = (size_t)BB*TT*LL*256;   // f32, unpadded
// seq aliases the dead z0 region after the layer-in GEMM (padded pitch 1538):
static constexpr size_t OFF_SEQ   = OFF_Z0HI;               // f32 [28][1538][64]
static constexpr size_t OFF_SEQHI = OFF_SEQ + (size_t)BB*TT*LL2*64;
static constexpr size_t OFF_SEQLO = OFF_SEQHI + (size_t)BB*TT*LL2*32;
// total ~96.4 MB

__device__ __forceinline__ float hsig(float x) {
    return fminf(fmaxf(0.2f * x + 0.5f, 0.0f), 1.0f);
}
__device__ __forceinline__ float ftanh(float x) {
    // tanh(x) = 1 - 2/(e^{2x}+1); bounded, finite-in -> finite-out.
    float e = __expf(2.0f * x);
    return 1.0f - 2.0f / (e + 1.0f);
}
__device__ __forceinline__ unsigned short f2bf(float x) {
    unsigned int u = __builtin_bit_cast(unsigned int, x);
    u += 0x7fffu + ((u >> 16) & 1u);          // RNE
    return (unsigned short)(u >> 16);
}
__device__ __forceinline__ float bf2f(unsigned short h) {
    unsigned int u = ((unsigned int)h) << 16;
    return __builtin_bit_cast(float, u);
}
// async global->LDS: lane i of the wave writes lds_base + i*16 from its own
// per-lane global address (wave-uniform LDS base, per-lane global src).
__device__ __forceinline__ void gload_lds16(const void* g, void* l) {
    __builtin_amdgcn_global_load_lds(
        (const __attribute__((address_space(1))) unsigned int*)g,
        (__attribute__((address_space(3))) unsigned int*)l, 16, 0, 0);
}

// ---------------------------------------------------------------------------
// zero_pads: zero the halo pad rows (row 0 and row 1537) of the z0 planes.
// ---------------------------------------------------------------------------
__global__ __launch_bounds__(256)
void zero_pads_kernel(unsigned short* __restrict__ z0hi,
                      unsigned short* __restrict__ z0lo)
{
    int idx = blockIdx.x * 256 + threadIdx.x;
    const int NZ = BB * TT * 2 * CP_IN;        // 17920
    if (idx < NZ) {
        int c = idx % CP_IN, r2 = idx / CP_IN;
        int p = r2 >> 1, e = r2 & 1;
        long long off = ((long long)p * LL2 + (e ? (LL2 - 1) : 0)) * CP_IN + c;
        z0hi[off] = 0; z0lo[off] = 0;
    }
}

// ---------------------------------------------------------------------------
// zero_seq_pads: zero pad rows of the seq bf16 planes. MUST run after the
// layer-in GEMM (seq aliases z0). Stream order guarantees this.
// ---------------------------------------------------------------------------
__global__ __launch_bounds__(256)
void zero_seq_pads_kernel(unsigned short* __restrict__ seqhb,
                          unsigned short* __restrict__ seqlb)
{
    int idx = blockIdx.x * 256 + threadIdx.x;
    const int NS = BB * TT * 2 * 64;           // 3584
    if (idx < NS) {
        int c = idx % 64, r2 = idx / 64;
        int p = r2 >> 1, e = r2 & 1;
        long long off = ((long long)p * LL2 + (e ? (LL2 - 1) : 0)) * 64 + c;
        seqhb[off] = 0; seqlb[off] = 0;
    }
}

// ---------------------------------------------------------------------------
// prep_weights R17: Wx panels emitted FRAGMENT-MAJOR:
//   Bp[cc][kh][g][lane][8]  (lane = quad*16 + mm)
//   value = Wx row n = g*16+mm, channel ci = cc*32 + quad*8 + j
// Same bits as the old [n][k] layout -> bit-exact; same sizes/offsets.
// ---------------------------------------------------------------------------
__global__ __launch_bounds__(256)
void prep_weights_kernel(const float* wx_in, const float* wh_in, const float* b_in,
                         const float* wx_r0, const float* wh_r0, const float* b_r0,
                         const float* wx_r1, const float* wh_r1, const float* b_r1,
                         const float* wx_out, const float* wh_out, const float* b_out,
                         float* __restrict__ ws)
{
    int idx = blockIdx.x * 256 + threadIdx.x;
    unsigned short* u = (unsigned short*)ws;
    if (idx < 245760) {                         // BpIN: 480 frags x 512
        int j = idx & 7, lane = (idx >> 3) & 63, frag = idx >> 9;
        int g = frag & 15, rest = frag >> 4;    // rest = cc*3 + kh
        int kh = rest % 3, cc = rest / 3;
        int mm = lane & 15, quad = lane >> 4;
        int n = g * 16 + mm;
        int ci = cc * 32 + quad * 8 + j;
        float v = 0.0f;
        if (ci < CINR)
            v = wx_in[((size_t)(kh * 3 + 1) * CINR + ci) * 256 + (n & 3) * 64 + (n >> 2)];
        unsigned short hi = f2bf(v);
        u[U_WBIN_HI + idx] = hi;
        u[U_WBIN_LO + idx] = f2bf(v - bf2f(hi));
        return;
    }
    idx -= 245760;
    if (idx < 49152) {                          // BpR0: 96 frags x 512
        int j = idx & 7, lane = (idx >> 3) & 63, frag = idx >> 9;
        int g = frag & 15, rest = frag >> 4;
        int kh = rest % 3, cc = rest / 3;
        int mm = lane & 15, quad = lane >> 4;
        int n = g * 16 + mm;
        int ci = cc * 32 + quad * 8 + j;
        float v = wx_r0[((size_t)(kh * 3 + 1) * 64 + ci) * 256 + (n & 3) * 64 + (n >> 2)];
        unsigned short hi = f2bf(v);
        u[U_WBR0_HI + idx] = hi;
        u[U_WBR0_LO + idx] = f2bf(v - bf2f(hi));
        return;
    }
    idx -= 49152;
    if (idx < 49152) {                          // BpR1
        int j = idx & 7, lane = (idx >> 3) & 63, frag = idx >> 9;
        int g = frag & 15, rest = frag >> 4;
        int kh = rest % 3, cc = rest / 3;
        int mm = lane & 15, quad = lane >> 4;
        int n = g * 16 + mm;
        int ci = cc * 32 + quad * 8 + j;
        float v = wx_r1[((size_t)(kh * 3 + 1) * 64 + ci) * 256 + (n & 3) * 64 + (n >> 2)];
        unsigned short hi = f2bf(v);
        u[U_WBR1_HI + idx] = hi;
        u[U_WBR1_LO + idx] = f2bf(v - bf2f(hi));
        return;
    }
    idx -= 49152;
    if (idx < 24576) {                          // BpOUT: 48 frags x 512 (N=128)
        int j = idx & 7, lane = (idx >> 3) & 63, frag = idx >> 9;
        int g = frag & 7, rest = frag >> 3;
        int kh = rest % 3, cc = rest / 3;
        int mm = lane & 15, quad = lane >> 4;
        int n = g * 16 + mm;
        int ci = cc * 32 + quad * 8 + j;
        float v = wx_out[((size_t)(kh * 3 + 1) * 64 + ci) * 128 + (n & 3) * 32 + (n >> 2)];
        unsigned short hi = f2bf(v);
        u[U_WBOUT_HI + idx] = hi;
        u[U_WBOUT_LO + idx] = f2bf(v - bf2f(hi));
        return;
    }
    idx -= 24576;
    if (idx < 49152) {                          // WHTIN [256][192]
        int n = idx / 192, k = idx % 192, kh = k >> 6, ci = k & 63;
        u[U_WHTIN + idx] = f2bf(wh_in[((size_t)(kh * 3 + 1) * 64 + ci) * 256 + n]);
        return;
    }
    idx -= 49152;
    if (idx < 49152) {
        int n = idx / 192, k = idx % 192, kh = k >> 6, ci = k & 63;
        u[U_WHTR0 + idx] = f2bf(wh_r0[((size_t)(kh * 3 + 1) * 64 + ci) * 256 + n]);
        return;
    }
    idx -= 49152;
    if (idx < 49152) {
        int n = idx / 192, k = idx % 192, kh = k >> 6, ci = k & 63;
        u[U_WHTR1 + idx] = f2bf(wh_r1[((size_t)(kh * 3 + 1) * 64 + ci) * 256 + n]);
        return;
    }
    idx -= 49152;
    if (idx < 12288) {                          // WHTOUT [128][96]
        int n = idx / 96, k = idx % 96, kh = k / 32, ci = k % 32;
        u[U_WHTOUT + idx] = f2bf(wh_out[((size_t)(kh * 3 + 1) * 32 + ci) * 128 + n]);
        return;
    }
    idx -= 12288;
    if (idx < 256) { int f = idx >> 2, g = idx & 3; ws[OFF_BIN + idx] = b_in[g * 64 + f]; return; }
    idx -= 256;
    if (idx < 256) { int f = idx >> 2, g = idx & 3; ws[OFF_BR0 + idx] = b_r0[g * 64 + f]; return; }
    idx -= 256;
    if (idx < 256) { int f = idx >> 2, g = idx & 3; ws[OFF_BR1 + idx] = b_r1[g * 64 + f]; return; }
    idx -= 256;
    if (idx < 128) { int f = idx >> 2, g = idx & 3; ws[OFF_BOUT + idx] = b_out[g * 32 + f]; return; }
}

// ---------------------------------------------------------------------------
// build_features: gather -> z0 bf16 hi/lo, PADDED layout [28][1538][320]
// ---------------------------------------------------------------------------
__global__ __launch_bounds__(256)
void build_features_kernel(const float* __restrict__ y,
                           const float* __restrict__ h,
                           const float* __restrict__ ev,
                           const float* __restrict__ no,
                           unsigned short* __restrict__ z0hi,
                           unsigned short* __restrict__ z0lo)
{
    long long idx = (long long)blockIdx.x * 256 + threadIdx.x;
    const long long total = (long long)BB * TT * LL * CP_IN;
    if (idx >= total) return;
    int c = (int)(idx % CP_IN);
    long long rest = idx / CP_IN;
    int l = (int)(rest % LL); rest /= LL;
    int t = (int)(rest % TT);
    int b = (int)(rest / TT);
    float v = 0.0f;
    if (c < 32) {
        int na = c >> 1, ri = c & 1;
        v = y[((((long long)b * 16 + na) * TT + t) * LL + l) * 2 + ri];
    } else if (c < 288) {
        int q = c - 32;
        int ri = q & 1, nspu = (q >> 1) & 1, nue = (q >> 2) & 3, na = q >> 4;
        v = h[((((((long long)b * 16 + na) * 4 + nue) * 2 + nspu) * TT + t) * LL + l) * 2 + ri];
    } else if (c < 296) {
        int q = c - 288; int nspu = q & 1, nue = q >> 1;
        v = ev[(((long long)(nue * 2 + nspu) * TT + t) * LL) + l];
    } else if (c == 296) {
        v = no[0];
    }
    const long long widx = (((long long)(b * TT + t)) * LL2 + (l + 1)) * CP_IN + c;
    unsigned short hi = f2bf(v);
    z0hi[widx] = hi;
    z0lo[widx] = f2bf(v - bf2f(hi));
}

// ---------------------------------------------------------------------------
// xz_gemm_mfma R17 (verified): split-bf16 MFMA conv-GEMM, 64x128 tile.
// A: 64-channel macro-chunk staged coalesced into LDS (72-short pitch);
//    2 barriers per macro-chunk; prefetch for mc+1 issues AFTER the 2nd.
// B: fragment-major panel, one coalesced 1KB load per fragment.
// ---------------------------------------------------------------------------
template <int CP>
__global__ __launch_bounds__(256)
void xz_gemm_mfma_kernel(const unsigned short* __restrict__ Ahi,
                         const unsigned short* __restrict__ Alo,
                         const unsigned short* __restrict__ Bphi,
                         const unsigned short* __restrict__ Bplo,
                         const float* __restrict__ bias,
                         float* __restrict__ out, int Ncol)
{
    constexpr int NCm = CP / 64;      // 5 (CP=320) / 1 (CP=64)
    __shared__ unsigned short AsHi[66 * 72], AsLo[66 * 72];
    const int tid  = threadIdx.x;
    const int lane = tid & 63;
    const int wv   = tid >> 6;
    const int m    = lane & 15;
    const int quad = lane >> 4;
    const int bt   = blockIdx.y;
    const int l0   = blockIdx.x * 64;
    const int n0   = blockIdx.z * 128;
    const int NG   = Ncol >> 4;                  // fragment groups per (cc,kh)
    const int gBase = (n0 >> 4) + wv;            // + nt*4

    // --- A staging slots: 528 = 66 rows x 8 x16B. tid, tid+256, 512+tid(<16)
    const int r0s = tid >> 3,        c0 = (tid & 7) * 8;
    const int r1s = (tid + 256) >> 3, c1 = (tid & 7) * 8;   // (tid+256)&7 == tid&7
    const int r2s = 64 + (tid >> 3),  c2 = (tid & 7) * 8;   // slots 512..527 (tid<16)
    const long long aG0 = ((long long)bt * LL2 + l0 + r0s) * CP + c0;
    const long long aG1 = ((long long)bt * LL2 + l0 + r1s) * CP + c1;
    const long long aG2 = ((long long)bt * LL2 + l0 + r2s) * CP + c2;

    short8 g0h, g0l, g1h, g1l, g2h = (short8)0, g2l = (short8)0;

    // prologue: macro-chunk 0 -> regs
    g0h = *reinterpret_cast<const short8*>(&Ahi[aG0]);
    g0l = *reinterpret_cast<const short8*>(&Alo[aG0]);
    g1h = *reinterpret_cast<const short8*>(&Ahi[aG1]);
    g1l = *reinterpret_cast<const short8*>(&Alo[aG1]);
    if (tid < 16) {
        g2h = *reinterpret_cast<const short8*>(&Ahi[aG2]);
        g2l = *reinterpret_cast<const short8*>(&Alo[aG2]);
    }

    floatx4 acc[4][2];
#pragma unroll
    for (int i = 0; i < 4; i++)
#pragma unroll
        for (int j = 0; j < 2; j++) acc[i][j] = (floatx4){0.f, 0.f, 0.f, 0.f};

#pragma unroll 1
    for (int mc = 0; mc < NCm; ++mc) {
        __syncthreads();                 // previous macro-chunk's LDS reads done
        *reinterpret_cast<short8*>(&AsHi[r0s * 72 + c0]) = g0h;
        *reinterpret_cast<short8*>(&AsLo[r0s * 72 + c0]) = g0l;
        *reinterpret_cast<short8*>(&AsHi[r1s * 72 + c1]) = g1h;
        *reinterpret_cast<short8*>(&AsLo[r1s * 72 + c1]) = g1l;
        if (tid < 16) {
            *reinterpret_cast<short8*>(&AsHi[r2s * 72 + c2]) = g2h;
            *reinterpret_cast<short8*>(&AsLo[r2s * 72 + c2]) = g2l;
        }
        __syncthreads();                 // LDS tile ready
        // prefetch next macro-chunk NOW -> drains at NEXT iteration's barrier,
        // behind this iteration's 288-MFMA phase.
        if (mc + 1 < NCm) {
            const int co = (mc + 1) * 64;
            g0h = *reinterpret_cast<const short8*>(&Ahi[aG0 + co]);
            g0l = *reinterpret_cast<const short8*>(&Alo[aG0 + co]);
            g1h = *reinterpret_cast<const short8*>(&Ahi[aG1 + co]);
            g1l = *reinterpret_cast<const short8*>(&Alo[aG1 + co]);
            if (tid < 16) {
                g2h = *reinterpret_cast<const short8*>(&Ahi[aG2 + co]);
                g2l = *reinterpret_cast<const short8*>(&Alo[aG2 + co]);
            }
        }
#pragma unroll
        for (int sub = 0; sub < 2; ++sub) {
            const int cc = mc * 2 + sub;
            short8 bh[3][2], bl[3][2];
#pragma unroll
            for (int kh = 0; kh < 3; ++kh)
#pragma unroll
                for (int nt = 0; nt < 2; ++nt) {
                    const size_t off =
                        ((size_t)((cc * 3 + kh) * NG + gBase + nt * 4)) * 512 + lane * 8;
                    bh[kh][nt] = *reinterpret_cast<const short8*>(&Bphi[off]);
                    bl[kh][nt] = *reinterpret_cast<const short8*>(&Bplo[off]);
                }
#pragma unroll
            for (int kh = 0; kh < 3; ++kh) {
#pragma unroll
                for (int mt = 0; mt < 4; ++mt) {
                    const int aofs = (mt * 16 + m + kh) * 72 + sub * 32 + quad * 8;
                    const short8 ah = *reinterpret_cast<const short8*>(&AsHi[aofs]);
                    const short8 al = *reinterpret_cast<const short8*>(&AsLo[aofs]);
                    acc[mt][0] = __builtin_amdgcn_mfma_f32_16x16x32_bf16(al, bh[kh][0], acc[mt][0], 0, 0, 0);
                    acc[mt][0] = __builtin_amdgcn_mfma_f32_16x16x32_bf16(ah, bl[kh][0], acc[mt][0], 0, 0, 0);
                    acc[mt][0] = __builtin_amdgcn_mfma_f32_16x16x32_bf16(ah, bh[kh][0], acc[mt][0], 0, 0, 0);
                    acc[mt][1] = __builtin_amdgcn_mfma_f32_16x16x32_bf16(al, bh[kh][1], acc[mt][1], 0, 0, 0);
                    acc[mt][1] = __builtin_amdgcn_mfma_f32_16x16x32_bf16(ah, bl[kh][1], acc[mt][1], 0, 0, 0);
                    acc[mt][1] = __builtin_amdgcn_mfma_f32_16x16x32_bf16(ah, bh[kh][1], acc[mt][1], 0, 0, 0);
                }
            }
        }
    }

    // ---- epilogue ----
#pragma unroll
    for (int nt = 0; nt < 2; ++nt) {
        const int col = n0 + nt * 64 + wv * 16 + m;
        const float bv = bias[col];
#pragma unroll
        for (int mt = 0; mt < 4; ++mt) {
#pragma unroll
            for (int reg = 0; reg < 4; ++reg) {
                int l = l0 + mt * 16 + quad * 4 + reg;
                out[((size_t)bt * LL + l) * Ncol + col] = acc[mt][nt][reg] + bv;
            }
        }
    }
}

// ---------------------------------------------------------------------------
// lstm_scan R23 (trapezoid + LDS-double-buffered xz prefetch): 14 steps,
// zero inter-block sync, 192 blocks (own=16 @ window [16,32)), XCD-chunked
// swizzle. Step t: issue t+1's window (12 x 1KB global_load_lds per wave,
// uniform LDS base + per-lane global src) into Xs[nxt]; MFMA + gates read
// Xs[cur]; end barrier drains the loads behind the whole step's compute.
// Edge chunks never issued (LDS zeros persist). No frontier mask (garbage
// rows bounded; in-frontier rows identical) -> valid outputs bit-exact.
// ---------------------------------------------------------------------------
template <int F_, bool RESID, bool OUTW>
__global__ __launch_bounds__(64 * (F_ / 16))
void lstm_scan_kernel(const float* __restrict__ xz,           // [28][1536][4F] co'=f*4+g
                      const unsigned short* __restrict__ WhT, // [4F][3F] bf16
                      float* seq,                             // f32 layer in/out (padded pitch)
                      unsigned short* __restrict__ seqhb,     // bf16 hi out (padded pitch)
                      unsigned short* __restrict__ seqlb,     // bf16 lo out (padded pitch)
                      float* __restrict__ dout)               // final out (or null)
{
    constexpr int NW = F_ / 16;
    constexpr int NT = 64 * NW;
    constexpr int K  = 3 * F_;
    constexpr int KS = K / 32;          // 6 (F=64) / 3 (F=32)
    constexpr int KH = KS / 3;          // 2 / 1
    constexpr int HP = F_ + 8;
    constexpr int ROWF = 4 * F_;        // floats per xz row: 256 / 128
    constexpr int NCHK = WIN * ROWF / 256;  // 1KB chunks per buffer: 48 / 24
    constexpr int CPW  = NCHK / NW;         // chunks per wave: 12 / 12
    constexpr int RPC  = 256 / ROWF;        // rows per chunk: 1 / 2
    __shared__ unsigned short Hs[2][(WIN + 2) * HP];
    __shared__ float Xs[2][WIN * ROWF];     // 96KB (F=64) / 48KB (F=32)

    const int tid  = threadIdx.x;
    const int lane = tid & 63;
    const int wv   = tid >> 6;
    const int m    = lane & 15;
    const int quad = lane >> 4;
    // XCD-chunked swizzle (bijective: 192%8==0)
    const int blk  = (blockIdx.x & 7) * (NBLK / 8) + (blockIdx.x >> 3);
    const int b    = blk / NSTRIP;
    const int o0   = (blk % NSTRIP) * 16;   // own rows [o0, o0+16)
    const int f    = wv * 16 + m;

    // B-fragments resident for the whole scan
    short8 bfr[4][KS];
#pragma unroll
    for (int g = 0; g < 4; g++)
#pragma unroll
        for (int ks = 0; ks < KS; ks++) {
            const int n  = g * F_ + f;
            const int k0 = ks * 32 + quad * 8;
            bfr[g][ks] = *reinterpret_cast<const short8*>(&WhT[(size_t)n * K + k0]);
        }

    // zero Hs (halo slots stay 0 forever) and Xs (edge chunks never loaded)
    for (int idx = tid; idx < (WIN + 2) * HP; idx += NT) {
        Hs[0][idx] = 0; Hs[1][idx] = 0;
    }
    for (int idx = tid; idx < 2 * WIN * ROWF; idx += NT)
        (&Xs[0][0])[idx] = 0.0f;
    __syncthreads();                        // zeros visible before any DMA

    // issue t=0 window into Xs[0]
#pragma unroll
    for (int kk = 0; kk < CPW; ++kk) {
        const int k = wv * CPW + kk;        // wave-uniform chunk id
        const int l0c = o0 - 16 + k * RPC;
        if (l0c >= 0 && l0c + RPC <= LL) {
            const float* gp = xz + ((long long)b * TT * LL + l0c) * ROWF + lane * 4;
            gload_lds16(gp, &Xs[0][k * 256]);
        }
    }
    __syncthreads();                        // t=0 data resident

    float c[3][4];
#pragma unroll
    for (int i = 0; i < 3; i++)
#pragma unroll
        for (int j = 0; j < 4; j++) c[i][j] = 0.0f;

    int cur = 0;
    for (int t = 0; t < TT; ++t) {
        const size_t btL  = ((size_t)b * TT + t) * LL;    // dout (unpadded)
        const size_t btLP = ((size_t)b * TT + t) * LL2;   // seq planes (padded)

        // residual loads first (so their vmcnt wait leaves prefetch in flight)
        float rsv[4];
        if (RESID) {
#pragma unroll
            for (int reg = 0; reg < 4; ++reg) {
                const int l = o0 + quad * 4 + reg;          // own rows (mt=1)
                rsv[reg] = seq[(btLP + 1 + l) * F_ + f];
            }
        }

        const int nxt = cur ^ 1;
        // issue t+1's window -> Xs[nxt]; drains at this step's end barrier
        if (t + 1 < TT) {
#pragma unroll
            for (int kk = 0; kk < CPW; ++kk) {
                const int k = wv * CPW + kk;
                const int l0c = o0 - 16 + k * RPC;
                if (l0c >= 0 && l0c + RPC <= LL) {
                    const float* gp = xz + (((long long)b * TT + t + 1) * LL + l0c) * ROWF
                                    + lane * 4;
                    gload_lds16(gp, &Xs[nxt][k * 256]);
                }
            }
        }

#pragma unroll
        for (int mt = 0; mt < 3; ++mt) {
            floatx4 zi = {0.f, 0.f, 0.f, 0.f};
            floatx4 zf = {0.f, 0.f, 0.f, 0.f};
            floatx4 zg = {0.f, 0.f, 0.f, 0.f};
            floatx4 zo = {0.f, 0.f, 0.f, 0.f};
            if (t > 0) {
#pragma unroll
                for (int kh = 0; kh < 3; kh++) {
#pragma unroll
                    for (int hf = 0; hf < KH; hf++) {
                        const short8 af = *reinterpret_cast<const short8*>(
                            &Hs[cur][(mt * 16 + m + kh) * HP + hf * 32 + quad * 8]);
                        const int ks = kh * KH + hf;
                        zi = __builtin_amdgcn_mfma_f32_16x16x32_bf16(af, bfr[0][ks], zi, 0, 0, 0);
                        zf = __builtin_amdgcn_mfma_f32_16x16x32_bf16(af, bfr[1][ks], zf, 0, 0, 0);
                        zg = __builtin_amdgcn_mfma_f32_16x16x32_bf16(af, bfr[2][ks], zg, 0, 0, 0);
                        zo = __builtin_amdgcn_mfma_f32_16x16x32_bf16(af, bfr[3][ks], zo, 0, 0, 0);
                    }
                }
            }
#pragma unroll
            for (int reg = 0; reg < 4; ++reg) {
                const int w = mt * 16 + quad * 4 + reg;
                const int l = o0 - 16 + w;
                const bool valid = (l >= 0 && l < LL);
                const float4 z4 = *reinterpret_cast<const float4*>(
                    &Xs[cur][w * ROWF + f * 4]);
                const float ig = hsig(z4.x + zi[reg]);
                const float fg = hsig(z4.y + zf[reg]);
                const float gg = ftanh(z4.z + zg[reg]);
                const float og = hsig(z4.w + zo[reg]);
                float cn = fg * c[mt][reg] + ig * gg;
                float hn = og * ftanh(cn);
                if (!valid) { cn = 0.0f; hn = 0.0f; }   // exact conv pad
                c[mt][reg] = cn;
                Hs[nxt][(1 + w) * HP + f] = f2bf(hn);
                if (w >= 16 && w < 32) {                // own rows -> outputs
                    if (OUTW) {
                        const int ue = f >> 3, spu = (f >> 2) & 1, bit = f & 3;
                        const size_t n = (size_t)t * LL + l;
                        dout[(((size_t)b * 4 + ue) * 2 + spu) * ((size_t)TT * LL * 4)
                             + n * 4 + bit] = hn;
                    } else {
                        float v = hn;
                        if (RESID) v += rsv[reg];
                        seq[(btLP + 1 + l) * F_ + f] = v;
                        const unsigned short hi2 = f2bf(v);
                        seqhb[(btLP + 1 + l) * F_ + f] = hi2;
                        seqlb[(btLP + 1 + l) * F_ + f] = f2bf(v - bf2f(hi2));
                    }
                }
            }
        }
        __syncthreads();        // Hs[nxt] complete + Xs[nxt] DMA drained
        cur = nxt;
    }
}

// ---------------------------------------------------------------------------
extern "C" void kernel_launch(void* const* d_in, const int* in_sizes, int n_in,
                              void* d_out, int out_size, void* d_ws, size_t ws_size,
                              hipStream_t stream)
{
    (void)in_sizes; (void)n_in; (void)out_size; (void)ws_size;
    const float* y_ri   = (const float*)d_in[0];
    const float* h_ri   = (const float*)d_in[1];
    const float* evar   = (const float*)d_in[2];
    const float* no     = (const float*)d_in[3];
    const float* wx_in  = (const float*)d_in[4];
    const float* wh_in  = (const float*)d_in[5];
    const float* b_in   = (const float*)d_in[6];
    const float* wx_r0  = (const float*)d_in[7];
    const float* wh_r0  = (const float*)d_in[8];
    const float* b_r0   = (const float*)d_in[9];
    const float* wx_r1  = (const float*)d_in[10];
    const float* wh_r1  = (const float*)d_in[11];
    const float* b_r1   = (const float*)d_in[12];
    const float* wx_out = (const float*)d_in[13];
    const float* wh_out = (const float*)d_in[14];
    const float* b_out  = (const float*)d_in[15];

    float* ws = (float*)d_ws;
    unsigned short* wu = (unsigned short*)d_ws;
    float* dout = (float*)d_out;

    unsigned short* z0hi = (unsigned short*)(ws + OFF_Z0HI);
    unsigned short* z0lo = (unsigned short*)(ws + OFF_Z0LO);
    float* xz    = ws + OFF_XZ;
    float* seq   = ws + OFF_SEQ;
    unsigned short* seqhb = (unsigned short*)(ws + OFF_SEQHI);
    unsigned short* seqlb = (unsigned short*)(ws + OFF_SEQLO);

    zero_pads_kernel<<<70, 256, 0, stream>>>(z0hi, z0lo);
    prep_weights_kernel<<<2068, 256, 0, stream>>>(
        wx_in, wh_in, b_in, wx_r0, wh_r0, b_r0,
        wx_r1, wh_r1, b_r1, wx_out, wh_out, b_out, ws);
    {
        long long total = (long long)BB * TT * LL * CP_IN;
        int blocks = (int)((total + 255) / 256);
        build_features_kernel<<<blocks, 256, 0, stream>>>(
            y_ri, h_ri, evar, no, z0hi, z0lo);
    }

    const dim3 gIn(LL / 64, BB * TT, 2);    // N=256, 128 cols/block
    const dim3 gO (LL / 64, BB * TT, 1);    // N=128, 128 cols/block

    // ---- layer in: Cin=297(p320) -> F=64
    xz_gemm_mfma_kernel<CP_IN><<<gIn, 256, 0, stream>>>(
        z0hi, z0lo, wu + U_WBIN_HI, wu + U_WBIN_LO, ws + OFF_BIN, xz, 256);
    // seq pads alias z0 data -> zero them only now that z0 is consumed.
    zero_seq_pads_kernel<<<14, 256, 0, stream>>>(seqhb, seqlb);
    lstm_scan_kernel<64, false, false><<<NBLK, 256, 0, stream>>>(
        xz, wu + U_WHTIN, seq, seqhb, seqlb, nullptr);

    // ---- layer r0 (+residual, in-place on seq)
    xz_gemm_mfma_kernel<64><<<gIn, 256, 0, stream>>>(
        seqhb, seqlb, wu + U_WBR0_HI, wu + U_WBR0_LO, ws + OFF_BR0, xz, 256);
    lstm_scan_kernel<64, true, false><<<NBLK, 256, 0, stream>>>(
        xz, wu + U_WHTR0, seq, seqhb, seqlb, nullptr);

    // ---- layer r1 (+residual, in-place on seq)
    xz_gemm_mfma_kernel<64><<<gIn, 256, 0, stream>>>(
        seqhb, seqlb, wu + U_WBR1_HI, wu + U_WBR1_LO, ws + OFF_BR1, xz, 256);
    lstm_scan_kernel<64, true, false><<<NBLK, 256, 0, stream>>>(
        xz, wu + U_WHTR1, seq, seqhb, seqlb, nullptr);

    // ---- layer out: F=32, writes d_out (f32, transposed layout)
    xz_gemm_mfma_kernel<64><<<gO, 256, 0, stream>>>(
        seqhb, seqlb, wu + U_WBOUT_HI, wu + U_WBOUT_LO, ws + OFF_BOUT, xz, 128);
    lstm_scan_kernel<32, false, true><<<NBLK, 128, 0, stream>>>(
        xz, wu + U_WHTOUT, nullptr, nullptr, nullptr, dout);
}

// Round 13
// 464.671 us; speedup vs baseline: 1.0746x; 1.0746x over previous
//
#include <hip/hip_runtime.h>
#include <hip/hip_bf16.h>

// ---------------------------------------------------------------------------
// PUSCH neural detector: 4 stacked ConvLSTM layers on [B=2,T=14,H=1536,W=1].
// 3x3 conv degenerates to width-3 conv along H (kw=1 slice).
// R17 (482us): GEMM = A macro-chunk LDS + fragment-major B global->VGPR;
// scan = trapezoid (OWN=16, WIN=48, 192 blocks). Scan ladder: R18/R23 load
// prefetch neutral x3, R19 wave-split neutral, R21 fine-strips HBM-bound,
// R22 XCD-swizzle neutral. The model consistent with ALL SIX: each step's
// __syncthreads() drains vmcnt(0) -> the 12 per-thread GLOBAL STORES
// (seq/seqhb/seqlb, 2B-scattered) must retire to L2 before any wave starts
// the next step. R24: replace the step barrier with lgkmcnt(0)-only drain +
// raw s_barrier — LDS Hs ordering (the barrier's only in-kernel purpose)
// preserved exactly; store-acks pipeline across steps. Races: only
// cross-wave channel is Hs (ds_write -> lgkmcnt(0) -> s_barrier -> ds_read,
// covered); Hs[cur]/Hs[nxt] disjoint; global stores have no in-kernel
// readers. Same ops, same order per output -> bit-exact (absmax 1.95e-3).
// ---------------------------------------------------------------------------

#define BB   2
#define TT   14
#define LL   1536
#define LL2  1538                 // padded rows: zero row 0, zero row 1537
#define CINR 297
#define CP_IN 320                 // padded input channels (10 chunks of 32)
#define NSTRIP 96                 // LL / 16
#define NBLK  (BB * NSTRIP)       // 192 scan blocks
#define WIN  48                   // scan window rows (own 16 + 16 halo each side)

typedef __attribute__((ext_vector_type(8))) short short8;   // 8 bf16 = 4 VGPRs
typedef __attribute__((ext_vector_type(4))) float floatx4;  // MFMA C/D

// ---- workspace layout (float units) ---------------------------------------
static constexpr size_t U_WBIN_HI  = 0;         // Bp [10cc][3kh][16g][64lane][8]
static constexpr size_t U_WBIN_LO  = 245760;
static constexpr size_t U_WBR0_HI  = 491520;    // Bp [2][3][16][64][8]
static constexpr size_t U_WBR0_LO  = 540672;
static constexpr size_t U_WBR1_HI  = 589824;
static constexpr size_t U_WBR1_LO  = 638976;
static constexpr size_t U_WBOUT_HI = 688128;    // Bp [2][3][8][64][8]
static constexpr size_t U_WBOUT_LO = 712704;
static constexpr size_t U_WHTIN    = 737280;    // [256][192] scan WhT bf16
static constexpr size_t U_WHTR0    = 786432;
static constexpr size_t U_WHTR1    = 835584;
static constexpr size_t U_WHTOUT   = 884736;    // [128][96]
static constexpr size_t OFF_BIN   = 448512;     // f32 gate-interleaved biases
static constexpr size_t OFF_BR0   = 448768;
static constexpr size_t OFF_BR1   = 449024;
static constexpr size_t OFF_BOUT  = 449280;
static constexpr size_t OFF_Z0HI  = 458752;     // u16 plane [28][1538][320]
static constexpr size_t SZ_Z0PL   = 6890240;    // 28*1538*320/2 floats
static constexpr size_t OFF_Z0LO  = OFF_Z0HI + SZ_Z0PL;
static constexpr size_t OFF_XZ    = OFF_Z0LO + SZ_Z0PL;
static constexpr size_t SZ_XZ     = (size_t)BB*TT*LL*256;   // f32, unpadded
// seq aliases the dead z0 region after the layer-in GEMM (padded pitch 1538):
static constexpr size_t OFF_SEQ   = OFF_Z0HI;               // f32 [28][1538][64]
static constexpr size_t OFF_SEQHI = OFF_SEQ + (size_t)BB*TT*LL2*64;
static constexpr size_t OFF_SEQLO = OFF_SEQHI + (size_t)BB*TT*LL2*32;
// total ~96.4 MB

__device__ __forceinline__ float hsig(float x) {
    return fminf(fmaxf(0.2f * x + 0.5f, 0.0f), 1.0f);
}
__device__ __forceinline__ float ftanh(float x) {
    // tanh(x) = 1 - 2/(e^{2x}+1); bounded, finite-in -> finite-out.
    float e = __expf(2.0f * x);
    return 1.0f - 2.0f / (e + 1.0f);
}
__device__ __forceinline__ unsigned short f2bf(float x) {
    unsigned int u = __builtin_bit_cast(unsigned int, x);
    u += 0x7fffu + ((u >> 16) & 1u);          // RNE
    return (unsigned short)(u >> 16);
}
__device__ __forceinline__ float bf2f(unsigned short h) {
    unsigned int u = ((unsigned int)h) << 16;
    return __builtin_bit_cast(float, u);
}

// ---------------------------------------------------------------------------
// zero_pads: zero the halo pad rows (row 0 and row 1537) of the z0 planes.
// ---------------------------------------------------------------------------
__global__ __launch_bounds__(256)
void zero_pads_kernel(unsigned short* __restrict__ z0hi,
                      unsigned short* __restrict__ z0lo)
{
    int idx = blockIdx.x * 256 + threadIdx.x;
    const int NZ = BB * TT * 2 * CP_IN;        // 17920
    if (idx < NZ) {
        int c = idx % CP_IN, r2 = idx / CP_IN;
        int p = r2 >> 1, e = r2 & 1;
        long long off = ((long long)p * LL2 + (e ? (LL2 - 1) : 0)) * CP_IN + c;
        z0hi[off] = 0; z0lo[off] = 0;
    }
}

// ---------------------------------------------------------------------------
// zero_seq_pads: zero pad rows of the seq bf16 planes. MUST run after the
// layer-in GEMM (seq aliases z0). Stream order guarantees this.
// ---------------------------------------------------------------------------
__global__ __launch_bounds__(256)
void zero_seq_pads_kernel(unsigned short* __restrict__ seqhb,
                          unsigned short* __restrict__ seqlb)
{
    int idx = blockIdx.x * 256 + threadIdx.x;
    const int NS = BB * TT * 2 * 64;           // 3584
    if (idx < NS) {
        int c = idx % 64, r2 = idx / 64;
        int p = r2 >> 1, e = r2 & 1;
        long long off = ((long long)p * LL2 + (e ? (LL2 - 1) : 0)) * 64 + c;
        seqhb[off] = 0; seqlb[off] = 0;
    }
}

// ---------------------------------------------------------------------------
// prep_weights R17: Wx panels emitted FRAGMENT-MAJOR:
//   Bp[cc][kh][g][lane][8]  (lane = quad*16 + mm)
//   value = Wx row n = g*16+mm, channel ci = cc*32 + quad*8 + j
// Same bits as the old [n][k] layout -> bit-exact; same sizes/offsets.
// ---------------------------------------------------------------------------
__global__ __launch_bounds__(256)
void prep_weights_kernel(const float* wx_in, const float* wh_in, const float* b_in,
                         const float* wx_r0, const float* wh_r0, const float* b_r0,
                         const float* wx_r1, const float* wh_r1, const float* b_r1,
                         const float* wx_out, const float* wh_out, const float* b_out,
                         float* __restrict__ ws)
{
    int idx = blockIdx.x * 256 + threadIdx.x;
    unsigned short* u = (unsigned short*)ws;
    if (idx < 245760) {                         // BpIN: 480 frags x 512
        int j = idx & 7, lane = (idx >> 3) & 63, frag = idx >> 9;
        int g = frag & 15, rest = frag >> 4;    // rest = cc*3 + kh
        int kh = rest % 3, cc = rest / 3;
        int mm = lane & 15, quad = lane >> 4;
        int n = g * 16 + mm;
        int ci = cc * 32 + quad * 8 + j;
        float v = 0.0f;
        if (ci < CINR)
            v = wx_in[((size_t)(kh * 3 + 1) * CINR + ci) * 256 + (n & 3) * 64 + (n >> 2)];
        unsigned short hi = f2bf(v);
        u[U_WBIN_HI + idx] = hi;
        u[U_WBIN_LO + idx] = f2bf(v - bf2f(hi));
        return;
    }
    idx -= 245760;
    if (idx < 49152) {                          // BpR0: 96 frags x 512
        int j = idx & 7, lane = (idx >> 3) & 63, frag = idx >> 9;
        int g = frag & 15, rest = frag >> 4;
        int kh = rest % 3, cc = rest / 3;
        int mm = lane & 15, quad = lane >> 4;
        int n = g * 16 + mm;
        int ci = cc * 32 + quad * 8 + j;
        float v = wx_r0[((size_t)(kh * 3 + 1) * 64 + ci) * 256 + (n & 3) * 64 + (n >> 2)];
        unsigned short hi = f2bf(v);
        u[U_WBR0_HI + idx] = hi;
        u[U_WBR0_LO + idx] = f2bf(v - bf2f(hi));
        return;
    }
    idx -= 49152;
    if (idx < 49152) {                          // BpR1
        int j = idx & 7, lane = (idx >> 3) & 63, frag = idx >> 9;
        int g = frag & 15, rest = frag >> 4;
        int kh = rest % 3, cc = rest / 3;
        int mm = lane & 15, quad = lane >> 4;
        int n = g * 16 + mm;
        int ci = cc * 32 + quad * 8 + j;
        float v = wx_r1[((size_t)(kh * 3 + 1) * 64 + ci) * 256 + (n & 3) * 64 + (n >> 2)];
        unsigned short hi = f2bf(v);
        u[U_WBR1_HI + idx] = hi;
        u[U_WBR1_LO + idx] = f2bf(v - bf2f(hi));
        return;
    }
    idx -= 49152;
    if (idx < 24576) {                          // BpOUT: 48 frags x 512 (N=128)
        int j = idx & 7, lane = (idx >> 3) & 63, frag = idx >> 9;
        int g = frag & 7, rest = frag >> 3;
        int kh = rest % 3, cc = rest / 3;
        int mm = lane & 15, quad = lane >> 4;
        int n = g * 16 + mm;
        int ci = cc * 32 + quad * 8 + j;
        float v = wx_out[((size_t)(kh * 3 + 1) * 64 + ci) * 128 + (n & 3) * 32 + (n >> 2)];
        unsigned short hi = f2bf(v);
        u[U_WBOUT_HI + idx] = hi;
        u[U_WBOUT_LO + idx] = f2bf(v - bf2f(hi));
        return;
    }
    idx -= 24576;
    if (idx < 49152) {                          // WHTIN [256][192]
        int n = idx / 192, k = idx % 192, kh = k >> 6, ci = k & 63;
        u[U_WHTIN + idx] = f2bf(wh_in[((size_t)(kh * 3 + 1) * 64 + ci) * 256 + n]);
        return;
    }
    idx -= 49152;
    if (idx < 49152) {
        int n = idx / 192, k = idx % 192, kh = k >> 6, ci = k & 63;
        u[U_WHTR0 + idx] = f2bf(wh_r0[((size_t)(kh * 3 + 1) * 64 + ci) * 256 + n]);
        return;
    }
    idx -= 49152;
    if (idx < 49152) {
        int n = idx / 192, k = idx % 192, kh = k >> 6, ci = k & 63;
        u[U_WHTR1 + idx] = f2bf(wh_r1[((size_t)(kh * 3 + 1) * 64 + ci) * 256 + n]);
        return;
    }
    idx -= 49152;
    if (idx < 12288) {                          // WHTOUT [128][96]
        int n = idx / 96, k = idx % 96, kh = k / 32, ci = k % 32;
        u[U_WHTOUT + idx] = f2bf(wh_out[((size_t)(kh * 3 + 1) * 32 + ci) * 128 + n]);
        return;
    }
    idx -= 12288;
    if (idx < 256) { int f = idx >> 2, g = idx & 3; ws[OFF_BIN + idx] = b_in[g * 64 + f]; return; }
    idx -= 256;
    if (idx < 256) { int f = idx >> 2, g = idx & 3; ws[OFF_BR0 + idx] = b_r0[g * 64 + f]; return; }
    idx -= 256;
    if (idx < 256) { int f = idx >> 2, g = idx & 3; ws[OFF_BR1 + idx] = b_r1[g * 64 + f]; return; }
    idx -= 256;
    if (idx < 128) { int f = idx >> 2, g = idx & 3; ws[OFF_BOUT + idx] = b_out[g * 32 + f]; return; }
}

// ---------------------------------------------------------------------------
// build_features: gather -> z0 bf16 hi/lo, PADDED layout [28][1538][320]
// ---------------------------------------------------------------------------
__global__ __launch_bounds__(256)
void build_features_kernel(const float* __restrict__ y,
                           const float* __restrict__ h,
                           const float* __restrict__ ev,
                           const float* __restrict__ no,
                           unsigned short* __restrict__ z0hi,
                           unsigned short* __restrict__ z0lo)
{
    long long idx = (long long)blockIdx.x * 256 + threadIdx.x;
    const long long total = (long long)BB * TT * LL * CP_IN;
    if (idx >= total) return;
    int c = (int)(idx % CP_IN);
    long long rest = idx / CP_IN;
    int l = (int)(rest % LL); rest /= LL;
    int t = (int)(rest % TT);
    int b = (int)(rest / TT);
    float v = 0.0f;
    if (c < 32) {
        int na = c >> 1, ri = c & 1;
        v = y[((((long long)b * 16 + na) * TT + t) * LL + l) * 2 + ri];
    } else if (c < 288) {
        int q = c - 32;
        int ri = q & 1, nspu = (q >> 1) & 1, nue = (q >> 2) & 3, na = q >> 4;
        v = h[((((((long long)b * 16 + na) * 4 + nue) * 2 + nspu) * TT + t) * LL + l) * 2 + ri];
    } else if (c < 296) {
        int q = c - 288; int nspu = q & 1, nue = q >> 1;
        v = ev[(((long long)(nue * 2 + nspu) * TT + t) * LL) + l];
    } else if (c == 296) {
        v = no[0];
    }
    const long long widx = (((long long)(b * TT + t)) * LL2 + (l + 1)) * CP_IN + c;
    unsigned short hi = f2bf(v);
    z0hi[widx] = hi;
    z0lo[widx] = f2bf(v - bf2f(hi));
}

// ---------------------------------------------------------------------------
// xz_gemm_mfma R17 (verified): split-bf16 MFMA conv-GEMM, 64x128 tile.
// A: 64-channel macro-chunk staged coalesced into LDS (72-short pitch);
//    2 barriers per macro-chunk; prefetch for mc+1 issues AFTER the 2nd.
// B: fragment-major panel, one coalesced 1KB load per fragment.
// ---------------------------------------------------------------------------
template <int CP>
__global__ __launch_bounds__(256)
void xz_gemm_mfma_kernel(const unsigned short* __restrict__ Ahi,
                         const unsigned short* __restrict__ Alo,
                         const unsigned short* __restrict__ Bphi,
                         const unsigned short* __restrict__ Bplo,
                         const float* __restrict__ bias,
                         float* __restrict__ out, int Ncol)
{
    constexpr int NCm = CP / 64;      // 5 (CP=320) / 1 (CP=64)
    __shared__ unsigned short AsHi[66 * 72], AsLo[66 * 72];
    const int tid  = threadIdx.x;
    const int lane = tid & 63;
    const int wv   = tid >> 6;
    const int m    = lane & 15;
    const int quad = lane >> 4;
    const int bt   = blockIdx.y;
    const int l0   = blockIdx.x * 64;
    const int n0   = blockIdx.z * 128;
    const int NG   = Ncol >> 4;                  // fragment groups per (cc,kh)
    const int gBase = (n0 >> 4) + wv;            // + nt*4

    // --- A staging slots: 528 = 66 rows x 8 x16B. tid, tid+256, 512+tid(<16)
    const int r0s = tid >> 3,        c0 = (tid & 7) * 8;
    const int r1s = (tid + 256) >> 3, c1 = (tid & 7) * 8;   // (tid+256)&7 == tid&7
    const int r2s = 64 + (tid >> 3),  c2 = (tid & 7) * 8;   // slots 512..527 (tid<16)
    const long long aG0 = ((long long)bt * LL2 + l0 + r0s) * CP + c0;
    const long long aG1 = ((long long)bt * LL2 + l0 + r1s) * CP + c1;
    const long long aG2 = ((long long)bt * LL2 + l0 + r2s) * CP + c2;

    short8 g0h, g0l, g1h, g1l, g2h = (short8)0, g2l = (short8)0;

    // prologue: macro-chunk 0 -> regs
    g0h = *reinterpret_cast<const short8*>(&Ahi[aG0]);
    g0l = *reinterpret_cast<const short8*>(&Alo[aG0]);
    g1h = *reinterpret_cast<const short8*>(&Ahi[aG1]);
    g1l = *reinterpret_cast<const short8*>(&Alo[aG1]);
    if (tid < 16) {
        g2h = *reinterpret_cast<const short8*>(&Ahi[aG2]);
        g2l = *reinterpret_cast<const short8*>(&Alo[aG2]);
    }

    floatx4 acc[4][2];
#pragma unroll
    for (int i = 0; i < 4; i++)
#pragma unroll
        for (int j = 0; j < 2; j++) acc[i][j] = (floatx4){0.f, 0.f, 0.f, 0.f};

#pragma unroll 1
    for (int mc = 0; mc < NCm; ++mc) {
        __syncthreads();                 // previous macro-chunk's LDS reads done
        *reinterpret_cast<short8*>(&AsHi[r0s * 72 + c0]) = g0h;
        *reinterpret_cast<short8*>(&AsLo[r0s * 72 + c0]) = g0l;
        *reinterpret_cast<short8*>(&AsHi[r1s * 72 + c1]) = g1h;
        *reinterpret_cast<short8*>(&AsLo[r1s * 72 + c1]) = g1l;
        if (tid < 16) {
            *reinterpret_cast<short8*>(&AsHi[r2s * 72 + c2]) = g2h;
            *reinterpret_cast<short8*>(&AsLo[r2s * 72 + c2]) = g2l;
        }
        __syncthreads();                 // LDS tile ready
        // prefetch next macro-chunk NOW -> drains at NEXT iteration's barrier,
        // behind this iteration's 288-MFMA phase.
        if (mc + 1 < NCm) {
            const int co = (mc + 1) * 64;
            g0h = *reinterpret_cast<const short8*>(&Ahi[aG0 + co]);
            g0l = *reinterpret_cast<const short8*>(&Alo[aG0 + co]);
            g1h = *reinterpret_cast<const short8*>(&Ahi[aG1 + co]);
            g1l = *reinterpret_cast<const short8*>(&Alo[aG1 + co]);
            if (tid < 16) {
                g2h = *reinterpret_cast<const short8*>(&Ahi[aG2 + co]);
                g2l = *reinterpret_cast<const short8*>(&Alo[aG2 + co]);
            }
        }
#pragma unroll
        for (int sub = 0; sub < 2; ++sub) {
            const int cc = mc * 2 + sub;
            short8 bh[3][2], bl[3][2];
#pragma unroll
            for (int kh = 0; kh < 3; ++kh)
#pragma unroll
                for (int nt = 0; nt < 2; ++nt) {
                    const size_t off =
                        ((size_t)((cc * 3 + kh) * NG + gBase + nt * 4)) * 512 + lane * 8;
                    bh[kh][nt] = *reinterpret_cast<const short8*>(&Bphi[off]);
                    bl[kh][nt] = *reinterpret_cast<const short8*>(&Bplo[off]);
                }
#pragma unroll
            for (int kh = 0; kh < 3; ++kh) {
#pragma unroll
                for (int mt = 0; mt < 4; ++mt) {
                    const int aofs = (mt * 16 + m + kh) * 72 + sub * 32 + quad * 8;
                    const short8 ah = *reinterpret_cast<const short8*>(&AsHi[aofs]);
                    const short8 al = *reinterpret_cast<const short8*>(&AsLo[aofs]);
                    acc[mt][0] = __builtin_amdgcn_mfma_f32_16x16x32_bf16(al, bh[kh][0], acc[mt][0], 0, 0, 0);
                    acc[mt][0] = __builtin_amdgcn_mfma_f32_16x16x32_bf16(ah, bl[kh][0], acc[mt][0], 0, 0, 0);
                    acc[mt][0] = __builtin_amdgcn_mfma_f32_16x16x32_bf16(ah, bh[kh][0], acc[mt][0], 0, 0, 0);
                    acc[mt][1] = __builtin_amdgcn_mfma_f32_16x16x32_bf16(al, bh[kh][1], acc[mt][1], 0, 0, 0);
                    acc[mt][1] = __builtin_amdgcn_mfma_f32_16x16x32_bf16(ah, bl[kh][1], acc[mt][1], 0, 0, 0);
                    acc[mt][1] = __builtin_amdgcn_mfma_f32_16x16x32_bf16(ah, bh[kh][1], acc[mt][1], 0, 0, 0);
                }
            }
        }
    }

    // ---- epilogue ----
#pragma unroll
    for (int nt = 0; nt < 2; ++nt) {
        const int col = n0 + nt * 64 + wv * 16 + m;
        const float bv = bias[col];
#pragma unroll
        for (int mt = 0; mt < 4; ++mt) {
#pragma unroll
            for (int reg = 0; reg < 4; ++reg) {
                int l = l0 + mt * 16 + quad * 4 + reg;
                out[((size_t)bt * LL + l) * Ncol + col] = acc[mt][nt][reg] + bv;
            }
        }
    }
}

// ---------------------------------------------------------------------------
// lstm_scan R24 (trapezoid + raw step barrier): 14 steps, zero inter-block
// sync, 192 blocks (own=16 @ window [16,32)), XCD-chunked swizzle. The
// end-of-step barrier is lgkmcnt(0)-only + raw s_barrier: Hs LDS ordering
// preserved; the step's global stores (seq/seqhb/seqlb/dout) retire in the
// background instead of stalling all waves at a vmcnt(0) drain.
// ---------------------------------------------------------------------------
template <int F_, bool RESID, bool OUTW>
__global__ __launch_bounds__(64 * (F_ / 16))
void lstm_scan_kernel(const float* __restrict__ xz,           // [28][1536][4F] co'=f*4+g
                      const unsigned short* __restrict__ WhT, // [4F][3F] bf16
                      float* seq,                             // f32 layer in/out (padded pitch)
                      unsigned short* __restrict__ seqhb,     // bf16 hi out (padded pitch)
                      unsigned short* __restrict__ seqlb,     // bf16 lo out (padded pitch)
                      float* __restrict__ dout)               // final out (or null)
{
    constexpr int NW = F_ / 16;
    constexpr int NT = 64 * NW;
    constexpr int K  = 3 * F_;
    constexpr int KS = K / 32;          // 6 (F=64) / 3 (F=32)
    constexpr int KH = KS / 3;          // 2 / 1
    constexpr int HP = F_ + 8;
    __shared__ unsigned short Hs[2][(WIN + 2) * HP];

    const int tid  = threadIdx.x;
    const int lane = tid & 63;
    const int wv   = tid >> 6;
    const int m    = lane & 15;
    const int quad = lane >> 4;
    // XCD-chunked swizzle (bijective: 192%8==0)
    const int blk  = (blockIdx.x & 7) * (NBLK / 8) + (blockIdx.x >> 3);
    const int b    = blk / NSTRIP;
    const int o0   = (blk % NSTRIP) * 16;   // own rows [o0, o0+16)
    const int f    = wv * 16 + m;

    // B-fragments resident for the whole scan
    short8 bfr[4][KS];
#pragma unroll
    for (int g = 0; g < 4; g++)
#pragma unroll
        for (int ks = 0; ks < KS; ks++) {
            const int n  = g * F_ + f;
            const int k0 = ks * 32 + quad * 8;
            bfr[g][ks] = *reinterpret_cast<const short8*>(&WhT[(size_t)n * K + k0]);
        }

    for (int idx = tid; idx < (WIN + 2) * HP; idx += NT) {
        Hs[0][idx] = 0; Hs[1][idx] = 0;     // halo slots stay 0 forever
    }
    __syncthreads();

    float c[3][4];
#pragma unroll
    for (int i = 0; i < 3; i++)
#pragma unroll
        for (int j = 0; j < 4; j++) c[i][j] = 0.0f;

    int cur = 0;
    for (int t = 0; t < TT; ++t) {
        const size_t btL  = ((size_t)b * TT + t) * LL;    // xz / dout (unpadded)
        const size_t btLP = ((size_t)b * TT + t) * LL2;   // seq planes (padded)

        // prefetch xz for the whole step (predicated: image bounds + frontier)
        float4 xzv[3][4];
        float  rsv[4];
#pragma unroll
        for (int mt = 0; mt < 3; ++mt)
#pragma unroll
            for (int reg = 0; reg < 4; ++reg) {
                const int w = mt * 16 + quad * 4 + reg;
                const int l = o0 - 16 + w;
                float4 v = make_float4(0.f, 0.f, 0.f, 0.f);
                if (l >= 0 && l < LL && w >= t && w < WIN - t)
                    v = *reinterpret_cast<const float4*>(
                        &xz[(btL + l) * (size_t)(4 * F_) + f * 4]);
                xzv[mt][reg] = v;
            }
        if (RESID) {
#pragma unroll
            for (int reg = 0; reg < 4; ++reg) {
                const int l = o0 + quad * 4 + reg;          // own rows (mt=1)
                rsv[reg] = seq[(btLP + 1 + l) * F_ + f];
            }
        }

        const int nxt = cur ^ 1;
#pragma unroll
        for (int mt = 0; mt < 3; ++mt) {
            floatx4 zi = {0.f, 0.f, 0.f, 0.f};
            floatx4 zf = {0.f, 0.f, 0.f, 0.f};
            floatx4 zg = {0.f, 0.f, 0.f, 0.f};
            floatx4 zo = {0.f, 0.f, 0.f, 0.f};
            if (t > 0) {
#pragma unroll
                for (int kh = 0; kh < 3; kh++) {
#pragma unroll
                    for (int hf = 0; hf < KH; hf++) {
                        const short8 af = *reinterpret_cast<const short8*>(
                            &Hs[cur][(mt * 16 + m + kh) * HP + hf * 32 + quad * 8]);
                        const int ks = kh * KH + hf;
                        zi = __builtin_amdgcn_mfma_f32_16x16x32_bf16(af, bfr[0][ks], zi, 0, 0, 0);
                        zf = __builtin_amdgcn_mfma_f32_16x16x32_bf16(af, bfr[1][ks], zf, 0, 0, 0);
                        zg = __builtin_amdgcn_mfma_f32_16x16x32_bf16(af, bfr[2][ks], zg, 0, 0, 0);
                        zo = __builtin_amdgcn_mfma_f32_16x16x32_bf16(af, bfr[3][ks], zo, 0, 0, 0);
                    }
                }
            }
#pragma unroll
            for (int reg = 0; reg < 4; ++reg) {
                const int w = mt * 16 + quad * 4 + reg;
                const int l = o0 - 16 + w;
                const bool valid = (l >= 0 && l < LL);
                const float4 z4 = xzv[mt][reg];
                const float ig = hsig(z4.x + zi[reg]);
                const float fg = hsig(z4.y + zf[reg]);
                const float gg = ftanh(z4.z + zg[reg]);
                const float og = hsig(z4.w + zo[reg]);
                float cn = fg * c[mt][reg] + ig * gg;
                float hn = og * ftanh(cn);
                if (!valid) { cn = 0.0f; hn = 0.0f; }   // exact conv pad
                c[mt][reg] = cn;
                Hs[nxt][(1 + w) * HP + f] = f2bf(hn);
                if (w >= 16 && w < 32) {                // own rows -> outputs
                    if (OUTW) {
                        const int ue = f >> 3, spu = (f >> 2) & 1, bit = f & 3;
                        const size_t n = (size_t)t * LL + l;
                        dout[(((size_t)b * 4 + ue) * 2 + spu) * ((size_t)TT * LL * 4)
                             + n * 4 + bit] = hn;
                    } else {
                        float v = hn;
                        if (RESID) v += rsv[reg];
                        seq[(btLP + 1 + l) * F_ + f] = v;
                        const unsigned short hi2 = f2bf(v);
                        seqhb[(btLP + 1 + l) * F_ + f] = hi2;
                        seqlb[(btLP + 1 + l) * F_ + f] = f2bf(v - bf2f(hi2));
                    }
                }
            }
        }
        // Raw step barrier: order the Hs[nxt] ds_writes (lgkmcnt only) and
        // rendezvous the waves WITHOUT draining the global stores (vmcnt) —
        // store-acks retire behind the next step's compute.
        asm volatile("s_waitcnt lgkmcnt(0)" ::: "memory");
        __builtin_amdgcn_s_barrier();
        cur = nxt;
    }
}

// ---------------------------------------------------------------------------
extern "C" void kernel_launch(void* const* d_in, const int* in_sizes, int n_in,
                              void* d_out, int out_size, void* d_ws, size_t ws_size,
                              hipStream_t stream)
{
    (void)in_sizes; (void)n_in; (void)out_size; (void)ws_size;
    const float* y_ri   = (const float*)d_in[0];
    const float* h_ri   = (const float*)d_in[1];
    const float* evar   = (const float*)d_in[2];
    const float* no     = (const float*)d_in[3];
    const float* wx_in  = (const float*)d_in[4];
    const float* wh_in  = (const float*)d_in[5];
    const float* b_in   = (const float*)d_in[6];
    const float* wx_r0  = (const float*)d_in[7];
    const float* wh_r0  = (const float*)d_in[8];
    const float* b_r0   = (const float*)d_in[9];
    const float* wx_r1  = (const float*)d_in[10];
    const float* wh_r1  = (const float*)d_in[11];
    const float* b_r1   = (const float*)d_in[12];
    const float* wx_out = (const float*)d_in[13];
    const float* wh_out = (const float*)d_in[14];
    const float* b_out  = (const float*)d_in[15];

    float* ws = (float*)d_ws;
    unsigned short* wu = (unsigned short*)d_ws;
    float* dout = (float*)d_out;

    unsigned short* z0hi = (unsigned short*)(ws + OFF_Z0HI);
    unsigned short* z0lo = (unsigned short*)(ws + OFF_Z0LO);
    float* xz    = ws + OFF_XZ;
    float* seq   = ws + OFF_SEQ;
    unsigned short* seqhb = (unsigned short*)(ws + OFF_SEQHI);
    unsigned short* seqlb = (unsigned short*)(ws + OFF_SEQLO);

    zero_pads_kernel<<<70, 256, 0, stream>>>(z0hi, z0lo);
    prep_weights_kernel<<<2068, 256, 0, stream>>>(
        wx_in, wh_in, b_in, wx_r0, wh_r0, b_r0,
        wx_r1, wh_r1, b_r1, wx_out, wh_out, b_out, ws);
    {
        long long total = (long long)BB * TT * LL * CP_IN;
        int blocks = (int)((total + 255) / 256);
        build_features_kernel<<<blocks, 256, 0, stream>>>(
            y_ri, h_ri, evar, no, z0hi, z0lo);
    }

    const dim3 gIn(LL / 64, BB * TT, 2);    // N=256, 128 cols/block
    const dim3 gO (LL / 64, BB * TT, 1);    // N=128, 128 cols/block

    // ---- layer in: Cin=297(p320) -> F=64
    xz_gemm_mfma_kernel<CP_IN><<<gIn, 256, 0, stream>>>(
        z0hi, z0lo, wu + U_WBIN_HI, wu + U_WBIN_LO, ws + OFF_BIN, xz, 256);
    // seq pads alias z0 data -> zero them only now that z0 is consumed.
    zero_seq_pads_kernel<<<14, 256, 0, stream>>>(seqhb, seqlb);
    lstm_scan_kernel<64, false, false><<<NBLK, 256, 0, stream>>>(
        xz, wu + U_WHTIN, seq, seqhb, seqlb, nullptr);

    // ---- layer r0 (+residual, in-place on seq)
    xz_gemm_mfma_kernel<64><<<gIn, 256, 0, stream>>>(
        seqhb, seqlb, wu + U_WBR0_HI, wu + U_WBR0_LO, ws + OFF_BR0, xz, 256);
    lstm_scan_kernel<64, true, false><<<NBLK, 256, 0, stream>>>(
        xz, wu + U_WHTR0, seq, seqhb, seqlb, nullptr);

    // ---- layer r1 (+residual, in-place on seq)
    xz_gemm_mfma_kernel<64><<<gIn, 256, 0, stream>>>(
        seqhb, seqlb, wu + U_WBR1_HI, wu + U_WBR1_LO, ws + OFF_BR1, xz, 256);
    lstm_scan_kernel<64, true, false><<<NBLK, 256, 0, stream>>>(
        xz, wu + U_WHTR1, seq, seqhb, seqlb, nullptr);

    // ---- layer out: F=32, writes d_out (f32, transposed layout)
    xz_gemm_mfma_kernel<64><<<gO, 256, 0, stream>>>(
        seqhb, seqlb, wu + U_WBOUT_HI, wu + U_WBOUT_LO, ws + OFF_BOUT, xz, 128);
    lstm_scan_kernel<32, false, true><<<NBLK, 128, 0, stream>>>(
        xz, wu + U_WHTOUT, nullptr, nullptr, nullptr, dout);
}